// Round 2
// baseline (778.714 us; speedup 1.0000x reference)
//
#include <hip/hip_runtime.h>
#include <math.h>

#define NTOK   1000000
#define NFEAT  128
#define NCLUS  64
#define TT     256                       // tokens per tile (block)
#define KC     32                        // feature chunk staged in LDS
#define XPAD   260                       // x-tile row pad: 16B-aligned, conflict-free
#define NTILES ((NTOK + TT - 1) / TT)    // 3907 (last tile: 64 valid tokens)

// ---------------------------------------------------------------------------
// Kernel 1: one 256-token tile per block. Per-thread 8x8 register tile:
// 4 ds_read_b128 per 64 FMA. Exact fp32 d2 = x2 + c2 - 2*dot.
// ---------------------------------------------------------------------------
__global__ __launch_bounds__(256, 3)
void cluster_part_kernel(const float* __restrict__ x, const float* __restrict__ cc,
                         float* __restrict__ pv, int* __restrict__ pi)
{
    __shared__ float xs[KC][XPAD];   // 33280 B, feature-major x chunk
    __shared__ float cs[KC][NCLUS];  //  8192 B, feature-major c chunk
    __shared__ float x2s[TT];        //  1024 B, full ||x||^2 per token
    __shared__ float c2s[NCLUS];     //   256 B

    const int tid = threadIdx.x;
    const int cg  = tid & 7;    // cluster group: clusters cg*8 .. cg*8+7
    const int tg  = tid >> 3;   // token group:   tokens   tg*8 .. tg*8+7 (in tile)
    const int l   = tid & 3;    // staging sub-lane
    const int g   = tid >> 2;   // staging row 0..63

    const int  tile = blockIdx.x;
    const long tb   = (long)tile * TT;

    float acc[8][8];
    #pragma unroll
    for (int i = 0; i < 8; ++i)
        #pragma unroll
        for (int j = 0; j < 8; ++j) acc[i][j] = 0.f;

    for (int kc = 0; kc < NFEAT / KC; ++kc) {
        __syncthreads();   // protect LDS from previous chunk's readers

        // ---- stage c chunk: cluster g, features kc*32 + l*4 (+16) ----
        {
            const float* src = cc + (long)g * NFEAT + kc * KC + l * 4;
            float4 a = *(const float4*)(src);
            float4 b = *(const float4*)(src + 16);
            cs[l*4+0][g] = a.x; cs[l*4+1][g] = a.y;
            cs[l*4+2][g] = a.z; cs[l*4+3][g] = a.w;
            cs[16+l*4+0][g] = b.x; cs[16+l*4+1][g] = b.y;
            cs[16+l*4+2][g] = b.z; cs[16+l*4+3][g] = b.w;
            float s = 0.f;
            s = fmaf(a.x, a.x, s); s = fmaf(a.y, a.y, s);
            s = fmaf(a.z, a.z, s); s = fmaf(a.w, a.w, s);
            s = fmaf(b.x, b.x, s); s = fmaf(b.y, b.y, s);
            s = fmaf(b.z, b.z, s); s = fmaf(b.w, b.w, s);
            s += __shfl_xor(s, 1);
            s += __shfl_xor(s, 2);
            if (l == 0) { if (kc == 0) c2s[g] = s; else c2s[g] += s; }
        }

        // ---- stage x chunk: 4 rounds of 64 rows ----
        #pragma unroll
        for (int r = 0; r < 4; ++r) {
            const int  row = r * 64 + g;
            long n = tb + row;
            if (n > NTOK - 1) n = NTOK - 1;          // clamp tail (guarded later)
            const float* src = x + n * NFEAT + kc * KC + l * 4;
            float4 a = *(const float4*)(src);
            float4 b = *(const float4*)(src + 16);
            xs[l*4+0][row] = a.x; xs[l*4+1][row] = a.y;
            xs[l*4+2][row] = a.z; xs[l*4+3][row] = a.w;
            xs[16+l*4+0][row] = b.x; xs[16+l*4+1][row] = b.y;
            xs[16+l*4+2][row] = b.z; xs[16+l*4+3][row] = b.w;
            float s = 0.f;
            s = fmaf(a.x, a.x, s); s = fmaf(a.y, a.y, s);
            s = fmaf(a.z, a.z, s); s = fmaf(a.w, a.w, s);
            s = fmaf(b.x, b.x, s); s = fmaf(b.y, b.y, s);
            s = fmaf(b.z, b.z, s); s = fmaf(b.w, b.w, s);
            s += __shfl_xor(s, 1);
            s += __shfl_xor(s, 2);
            if (l == 0) { if (kc == 0) x2s[row] = s; else x2s[row] += s; }
        }
        __syncthreads();

        // ---- compute: 32 k-steps, 4 ds_read_b128 + 64 fmaf each ----
        #pragma unroll 2
        for (int k = 0; k < KC; ++k) {
            float4 xa = *(const float4*)&xs[k][tg * 8];
            float4 xb = *(const float4*)&xs[k][tg * 8 + 4];
            float4 ca = *(const float4*)&cs[k][cg * 8];
            float4 cb = *(const float4*)&cs[k][cg * 8 + 4];
            float xv[8] = {xa.x, xa.y, xa.z, xa.w, xb.x, xb.y, xb.z, xb.w};
            float cv[8] = {ca.x, ca.y, ca.z, ca.w, cb.x, cb.y, cb.z, cb.w};
            #pragma unroll
            for (int i = 0; i < 8; ++i)
                #pragma unroll
                for (int j = 0; j < 8; ++j)
                    acc[i][j] = fmaf(xv[i], cv[j], acc[i][j]);
        }
    }

    // ---- epilogue: per-thread argmin over my 8 tokens, per cluster slot ----
    float bestv[8]; int besti[8];
    #pragma unroll
    for (int j = 0; j < 8; ++j) { bestv[j] = INFINITY; besti[j] = 0; }

    float c2r[8];
    #pragma unroll
    for (int j = 0; j < 8; ++j) c2r[j] = c2s[cg * 8 + j];

    #pragma unroll
    for (int i = 0; i < 8; ++i) {
        const long n = tb + tg * 8 + i;
        if (n >= NTOK) continue;                     // tail guard
        const float x2 = x2s[tg * 8 + i];
        #pragma unroll
        for (int j = 0; j < 8; ++j) {
            float s = (x2 + c2r[j]) - 2.0f * acc[i][j];
            if (s < bestv[j]) { bestv[j] = s; besti[j] = (int)n; }  // strict <: earliest n
        }
    }

    // ---- block reduction: 32 token-groups per cluster ----
    __syncthreads();
    float* rv = &xs[0][0];        // [64 clusters][32 tg] = 8 KB (inside xs)
    int*   ri = (int*)&cs[0][0];  // 8 KB = exactly cs
    #pragma unroll
    for (int j = 0; j < 8; ++j) {
        rv[(cg * 8 + j) * 32 + tg] = bestv[j];
        ri[(cg * 8 + j) * 32 + tg] = besti[j];
    }
    __syncthreads();
    if (tid < NCLUS) {
        float bv = rv[tid * 32]; int bi = ri[tid * 32];
        #pragma unroll
        for (int t = 1; t < 32; ++t) {
            float v = rv[tid * 32 + t]; int ii = ri[tid * 32 + t];
            if (v < bv || (v == bv && ii < bi)) { bv = v; bi = ii; }
        }
        pv[(long)tile * NCLUS + tid] = bv;
        pi[(long)tile * NCLUS + tid] = bi;
    }
}

// ---------------------------------------------------------------------------
// Kernel 2: final reduce over NTILES partials per cluster + gather x[best]
// ---------------------------------------------------------------------------
__global__ __launch_bounds__(256)
void cluster_final_kernel(const float* __restrict__ x,
                          const float* __restrict__ pv, const int* __restrict__ pi,
                          float* __restrict__ out)
{
    const int c   = blockIdx.x;    // cluster 0..63
    const int tid = threadIdx.x;
    __shared__ float sv[256];
    __shared__ int   si[256];

    float bv = INFINITY; int bi = 0x7fffffff;
    for (int b = tid; b < NTILES; b += 256) {
        float v = pv[(long)b * NCLUS + c]; int ii = pi[(long)b * NCLUS + c];
        if (v < bv || (v == bv && ii < bi)) { bv = v; bi = ii; }
    }
    sv[tid] = bv; si[tid] = bi;
    __syncthreads();
    for (int s = 128; s > 0; s >>= 1) {
        if (tid < s) {
            float v = sv[tid + s]; int ii = si[tid + s];
            if (v < sv[tid] || (v == sv[tid] && ii < si[tid])) {
                sv[tid] = v; si[tid] = ii;
            }
        }
        __syncthreads();
    }
    const int best = si[0];
    if (tid < NFEAT) out[c * NFEAT + tid] = x[(long)best * NFEAT + tid];
}

extern "C" void kernel_launch(void* const* d_in, const int* in_sizes, int n_in,
                              void* d_out, int out_size, void* d_ws, size_t ws_size,
                              hipStream_t stream) {
    const float* x  = (const float*)d_in[0];   // (1, 1000000, 128) f32
    const float* cc = (const float*)d_in[1];   // (64, 128) f32
    float* out = (float*)d_out;                // (1, 64, 128) f32

    float* pv = (float*)d_ws;                                   // NTILES*64 f32
    int*   pi = (int*)((char*)d_ws + (size_t)NTILES * NCLUS * sizeof(float));

    cluster_part_kernel<<<NTILES, 256, 0, stream>>>(x, cc, pv, pi);
    cluster_final_kernel<<<NCLUS, 256, 0, stream>>>(x, pv, pi, out);
}

// Round 3
// 728.195 us; speedup vs baseline: 1.0694x; 1.0694x over previous
//
#include <hip/hip_runtime.h>
#include <math.h>

#define NTOK   1000000
#define NFEAT  128
#define NCLUS  64
#define TT     256                       // tokens per tile
#define KC     16                        // feature chunk staged in LDS
#define NCHUNK (NFEAT / KC)              // 8
#define XPAD   260                       // pad: 2-way banks only (free)
#define NTILES ((NTOK + TT - 1) / TT)    // 3907 (last tile: 64 valid tokens)
#define GRID_P 768                       // persistent blocks, 3 per CU

__global__ void zero_ctr_kernel(int* ctr) { *ctr = 0; }

// ---------------------------------------------------------------------------
// Kernel 1: persistent blocks pull 256-token tiles from an atomic counter.
// c staged once (feature-major, 32 KB). x staged per 16-feature chunk with
// register prefetch of the next chunk overlapping compute. 8x8 register tile:
// 4 ds_read_b128 per 64 fmaf. Exact fp32 d2 = x2 + c2 - 2*dot.
// ---------------------------------------------------------------------------
__global__ __launch_bounds__(256, 3)
void cluster_part_kernel(const float* __restrict__ x, const float* __restrict__ cc,
                         int* __restrict__ ctr,
                         float* __restrict__ pv, int* __restrict__ pi)
{
    __shared__ float cs[NFEAT][NCLUS];   // 32 KB, feature-major centers (full K)
    __shared__ float xs[KC][XPAD];       // 16.6 KB, feature-major x chunk
    __shared__ float x2s[TT];            // 1 KB
    __shared__ float c2s[NCLUS];         // 256 B
    __shared__ int   tileno;

    const int tid = threadIdx.x;
    const int cg  = tid & 7;    // clusters cg*8 .. cg*8+7
    const int tg  = tid >> 3;   // tokens  tg*8 .. tg*8+7 (in tile)
    const int l   = tid & 3;    // staging sub-lane (16 B of a 64 B row-chunk)
    const int g   = tid >> 2;   // staging row 0..63

    // ---- stage ALL of c (transpose to feature-major) + c2, once ----
    {
        float s = 0.f;
        const float* src = cc + (long)g * NFEAT + l * 4;
        #pragma unroll
        for (int r = 0; r < 8; ++r) {
            float4 v = *(const float4*)(src + r * 16);
            const int f = r * 16 + l * 4;
            cs[f + 0][g] = v.x; cs[f + 1][g] = v.y;
            cs[f + 2][g] = v.z; cs[f + 3][g] = v.w;
            s = fmaf(v.x, v.x, s); s = fmaf(v.y, v.y, s);
            s = fmaf(v.z, v.z, s); s = fmaf(v.w, v.w, s);
        }
        s += __shfl_xor(s, 1);
        s += __shfl_xor(s, 2);
        if (l == 0) c2s[g] = s;
    }
    __syncthreads();

    float c2r[8];
    #pragma unroll
    for (int j = 0; j < 8; ++j) c2r[j] = c2s[cg * 8 + j];

    float bestv[8]; int besti[8];
    #pragma unroll
    for (int j = 0; j < 8; ++j) { bestv[j] = INFINITY; besti[j] = 0x7fffffff; }

    for (;;) {
        if (tid == 0) tileno = atomicAdd(ctr, 1);
        __syncthreads();                 // publish tileno; also fences xs reuse
        const int tile = tileno;
        if (tile >= NTILES) break;       // block-uniform
        const long tb = (long)tile * TT;

        // prefetch chunk 0 into registers
        float4 pf[4];
        #pragma unroll
        for (int r = 0; r < 4; ++r) {
            long n = tb + r * 64 + g;
            if (n >= NTOK) n = NTOK - 1;             // clamp tail (guarded later)
            pf[r] = *(const float4*)(x + n * NFEAT + l * 4);
        }

        float acc[8][8];
        #pragma unroll
        for (int i = 0; i < 8; ++i)
            #pragma unroll
            for (int j = 0; j < 8; ++j) acc[i][j] = 0.f;
        float x2a[4] = {0.f, 0.f, 0.f, 0.f};

        #pragma unroll 1
        for (int kc = 0; kc < NCHUNK; ++kc) {
            __syncthreads();             // previous chunk's readers done
            // write prefetched chunk kc, accumulate partial x2
            #pragma unroll
            for (int r = 0; r < 4; ++r) {
                float4 v = pf[r];
                const int row = r * 64 + g;
                xs[l * 4 + 0][row] = v.x; xs[l * 4 + 1][row] = v.y;
                xs[l * 4 + 2][row] = v.z; xs[l * 4 + 3][row] = v.w;
                x2a[r] = fmaf(v.x, v.x, x2a[r]);
                x2a[r] = fmaf(v.y, v.y, x2a[r]);
                x2a[r] = fmaf(v.z, v.z, x2a[r]);
                x2a[r] = fmaf(v.w, v.w, x2a[r]);
            }
            // issue prefetch of chunk kc+1 (waited at next iteration's writes)
            if (kc + 1 < NCHUNK) {
                #pragma unroll
                for (int r = 0; r < 4; ++r) {
                    long n = tb + r * 64 + g;
                    if (n >= NTOK) n = NTOK - 1;
                    pf[r] = *(const float4*)(x + n * NFEAT + (kc + 1) * KC + l * 4);
                }
            }
            __syncthreads();             // chunk kc visible

            const int kb = kc * KC;
            #pragma unroll 4
            for (int k = 0; k < KC; ++k) {
                float4 xa = *(const float4*)&xs[k][tg * 8];
                float4 xb = *(const float4*)&xs[k][tg * 8 + 4];
                float4 ca = *(const float4*)&cs[kb + k][cg * 8];
                float4 cb = *(const float4*)&cs[kb + k][cg * 8 + 4];
                float xv[8] = {xa.x, xa.y, xa.z, xa.w, xb.x, xb.y, xb.z, xb.w};
                float cv[8] = {ca.x, ca.y, ca.z, ca.w, cb.x, cb.y, cb.z, cb.w};
                #pragma unroll
                for (int i = 0; i < 8; ++i)
                    #pragma unroll
                    for (int j = 0; j < 8; ++j)
                        acc[i][j] = fmaf(xv[i], cv[j], acc[i][j]);
            }
        }

        // publish full x2 for this tile
        #pragma unroll
        for (int r = 0; r < 4; ++r) {
            float s = x2a[r];
            s += __shfl_xor(s, 1);
            s += __shfl_xor(s, 2);
            if (l == 0) x2s[r * 64 + g] = s;
        }
        __syncthreads();

        // epilogue: running argmin in registers
        #pragma unroll
        for (int i = 0; i < 8; ++i) {
            const long n = tb + tg * 8 + i;
            if (n >= NTOK) continue;                 // tail guard
            const float x2 = x2s[tg * 8 + i];
            #pragma unroll
            for (int j = 0; j < 8; ++j) {
                float s = (x2 + c2r[j]) - 2.0f * acc[i][j];
                if (s < bestv[j]) { bestv[j] = s; besti[j] = (int)n; }  // strict <
            }
        }
    }

    // ---- block reduction: 32 token-groups per cluster ----
    __syncthreads();
    float* rv = &xs[0][0];               // 2048 floats
    int*   ri = (int*)(&xs[0][0] + 2048);
    #pragma unroll
    for (int j = 0; j < 8; ++j) {
        rv[(cg * 8 + j) * 32 + tg] = bestv[j];
        ri[(cg * 8 + j) * 32 + tg] = besti[j];
    }
    __syncthreads();
    if (tid < NCLUS) {
        float bv = rv[tid * 32]; int bi = ri[tid * 32];
        #pragma unroll
        for (int t = 1; t < 32; ++t) {
            float v = rv[tid * 32 + t]; int ii = ri[tid * 32 + t];
            if (v < bv || (v == bv && ii < bi)) { bv = v; bi = ii; }
        }
        pv[(long)blockIdx.x * NCLUS + tid] = bv;
        pi[(long)blockIdx.x * NCLUS + tid] = bi;
    }
}

// ---------------------------------------------------------------------------
// Kernel 2: final reduce over GRID_P partials per cluster + gather x[best]
// ---------------------------------------------------------------------------
__global__ __launch_bounds__(256)
void cluster_final_kernel(const float* __restrict__ x,
                          const float* __restrict__ pv, const int* __restrict__ pi,
                          float* __restrict__ out)
{
    const int c   = blockIdx.x;
    const int tid = threadIdx.x;
    __shared__ float sv[256];
    __shared__ int   si[256];

    float bv = INFINITY; int bi = 0x7fffffff;
    for (int b = tid; b < GRID_P; b += 256) {
        float v = pv[(long)b * NCLUS + c]; int ii = pi[(long)b * NCLUS + c];
        if (v < bv || (v == bv && ii < bi)) { bv = v; bi = ii; }
    }
    sv[tid] = bv; si[tid] = bi;
    __syncthreads();
    for (int s = 128; s > 0; s >>= 1) {
        if (tid < s) {
            float v = sv[tid + s]; int ii = si[tid + s];
            if (v < sv[tid] || (v == sv[tid] && ii < si[tid])) {
                sv[tid] = v; si[tid] = ii;
            }
        }
        __syncthreads();
    }
    const int best = si[0];
    if (tid < NFEAT) out[c * NFEAT + tid] = x[(long)best * NFEAT + tid];
}

extern "C" void kernel_launch(void* const* d_in, const int* in_sizes, int n_in,
                              void* d_out, int out_size, void* d_ws, size_t ws_size,
                              hipStream_t stream) {
    const float* x  = (const float*)d_in[0];   // (1, 1000000, 128) f32
    const float* cc = (const float*)d_in[1];   // (64, 128) f32
    float* out = (float*)d_out;                // (1, 64, 128) f32

    int*   ctr = (int*)d_ws;                                        // [0,4)
    float* pv  = (float*)((char*)d_ws + 256);                       // GRID_P*64 f32
    int*   pi  = (int*)((char*)d_ws + 256 + (size_t)GRID_P * NCLUS * sizeof(float));

    zero_ctr_kernel<<<1, 1, 0, stream>>>(ctr);
    cluster_part_kernel<<<GRID_P, 256, 0, stream>>>(x, cc, ctr, pv, pi);
    cluster_final_kernel<<<NCLUS, 256, 0, stream>>>(x, pv, pi, out);
}